// Round 1
// baseline (219.722 us; speedup 1.0000x reference)
//
#include <hip/hip_runtime.h>
#include <math.h>

#define DD 5          // embedding dim
#define NFREQ 50      // frequencies per coordinate
// ENC_DIM = 4*NFREQ = 200; W row per gene = 200*5 = 1000 floats

// ---------------------------------------------------------------- init output
// out[c,g] = bias1[genes_oi[g]]; vectorized float4 (n_genes % 4 == 0)
__global__ void init_out_kernel(float* __restrict__ out,
                                const float* __restrict__ bias,
                                const int* __restrict__ genes_oi,
                                int n_genes, int total4) {
  int t = blockIdx.x * blockDim.x + threadIdx.x;
  if (t >= total4) return;
  int idx = t * 4;
  int j = idx % n_genes;          // n_genes multiple of 4 -> j..j+3 same row
  float4 v;
  v.x = bias[genes_oi[j + 0]];
  v.y = bias[genes_oi[j + 1]];
  v.z = bias[genes_oi[j + 2]];
  v.w = bias[genes_oi[j + 3]];
  reinterpret_cast<float4*>(out)[t] = v;
}

// ---------------------------------------------------------------- gene histogram
__global__ void hist_kernel(const int* __restrict__ gm, int F, int* __restrict__ cnt) {
  int t = blockIdx.x * blockDim.x + threadIdx.x;
  if (t < F) atomicAdd(&cnt[gm[t]], 1);
}

// ---------------------------------------------------------------- exclusive scan (n <= 1024)
__global__ void scan_kernel(const int* __restrict__ cnt, int n,
                            int* __restrict__ starts, int* __restrict__ cursors) {
  __shared__ int s[1024];
  int tid = threadIdx.x;
  int v = (tid < n) ? cnt[tid] : 0;
  s[tid] = v;
  __syncthreads();
  for (int off = 1; off < 1024; off <<= 1) {
    int t2 = (tid >= off) ? s[tid - off] : 0;
    __syncthreads();
    s[tid] += t2;
    __syncthreads();
  }
  if (tid < n) {
    int e = s[tid] - v;           // exclusive prefix
    starts[tid] = e;
    cursors[tid] = e;
  }
  if (tid == n - 1) starts[n] = s[tid];
}

// ---------------------------------------------------------------- scatter fragment ids by gene
__global__ void scatter_idx_kernel(const int* __restrict__ gm, int F,
                                   int* __restrict__ cursors, int* __restrict__ order) {
  int t = blockIdx.x * blockDim.x + threadIdx.x;
  if (t < F) {
    int p = atomicAdd(&cursors[gm[t]], 1);
    order[p] = t;
  }
}

// ---------------------------------------------------------------- fragment embedding
// One block per gene: W addresses are wave-uniform -> scalar (SMEM) loads.
__global__ __launch_bounds__(256) void embed_kernel(
    const float2* __restrict__ coords, const int* __restrict__ order,
    const int* __restrict__ starts, const float* __restrict__ W,
    float* __restrict__ emb) {
  int g = blockIdx.x;
  int s0 = starts[g];
  int s1 = starts[g + 1];
  const float* __restrict__ Wg = W + (size_t)g * (4 * NFREQ * DD);

  for (int i = s0 + threadIdx.x; i < s1; i += blockDim.x) {
    int f = order[i];
    float2 xy = coords[f];
    float a0d0 = 0.f, a0d1 = 0.f, a0d2 = 0.f, a0d3 = 0.f, a0d4 = 0.f;
    for (int k = 0; k < NFREQ; ++k) {
      // freq_{k+1} = 1000^(-2(k+1)/50) = 2^(-0.398631371*(k+1))
      float fr = exp2f(-0.39863137f * (float)(k + 1));
      float ax = xy.x * fr;
      float ay = xy.y * fr;
      float sx = __sinf(ax), cx = __cosf(ax);
      float sy = __sinf(ay), cy = __cosf(ay);
      const float* w0s = Wg + (2 * k) * DD;               // coord0 sin row
      const float* w0c = w0s + DD;                        // coord0 cos row
      const float* w1s = Wg + (2 * NFREQ + 2 * k) * DD;   // coord1 sin row
      const float* w1c = w1s + DD;                        // coord1 cos row
      a0d0 += sx * w0s[0] + cx * w0c[0] + sy * w1s[0] + cy * w1c[0];
      a0d1 += sx * w0s[1] + cx * w0c[1] + sy * w1s[1] + cy * w1c[1];
      a0d2 += sx * w0s[2] + cx * w0c[2] + sy * w1s[2] + cy * w1c[2];
      a0d3 += sx * w0s[3] + cx * w0c[3] + sy * w1s[3] + cy * w1c[3];
      a0d4 += sx * w0s[4] + cx * w0c[4] + sy * w1s[4] + cy * w1c[4];
    }
    float* e = emb + (size_t)f * DD;
    e[0] = 1.f / (1.f + __expf(-a0d0));
    e[1] = 1.f / (1.f + __expf(-a0d1));
    e[2] = 1.f / (1.f + __expf(-a0d2));
    e[3] = 1.f / (1.f + __expf(-a0d3));
    e[4] = 1.f / (1.f + __expf(-a0d4));
  }
}

// ---------------------------------------------------------------- ragged self-attention
template <int SZ>
__device__ __forceinline__ void attn_group(const int* __restrict__ idx,
                                           float* __restrict__ emb) {
  int fid[SZ];
  float x[SZ][DD];
#pragma unroll
  for (int a = 0; a < SZ; ++a) {
    fid[a] = idx[a];
    const float* p = emb + (size_t)fid[a] * DD;
#pragma unroll
    for (int d = 0; d < DD; ++d) x[a][d] = p[d];
  }
  const float scale = rsqrtf((float)SZ);   // reference scales by sqrt(seq_len)
  float o[SZ][DD];
#pragma unroll
  for (int a = 0; a < SZ; ++a) {
    float sc[SZ];
    float m = -1e30f;
#pragma unroll
    for (int b = 0; b < SZ; ++b) {
      float dt = 0.f;
#pragma unroll
      for (int d = 0; d < DD; ++d) dt += x[a][d] * x[b][d];
      sc[b] = dt * scale;
      m = fmaxf(m, sc[b]);
    }
    float sum = 0.f;
#pragma unroll
    for (int b = 0; b < SZ; ++b) {
      sc[b] = __expf(sc[b] - m);
      sum += sc[b];
    }
    float inv = 1.f / sum;
#pragma unroll
    for (int d = 0; d < DD; ++d) {
      float acc = 0.f;
#pragma unroll
      for (int b = 0; b < SZ; ++b) acc += sc[b] * x[b][d];
      o[a][d] = acc * inv;
    }
  }
#pragma unroll
  for (int a = 0; a < SZ; ++a) {
    float* p = emb + (size_t)fid[a] * DD;
#pragma unroll
    for (int d = 0; d < DD; ++d) p[d] = o[a][d];
  }
}

__global__ void attn_kernel(const int* __restrict__ n2, int g2,
                            const int* __restrict__ n3, int g3,
                            const int* __restrict__ n4, int g4,
                            float* __restrict__ emb) {
  int t = blockIdx.x * blockDim.x + threadIdx.x;
  if (t < g2) {
    attn_group<2>(n2 + (size_t)t * 2, emb);
  } else if (t < g2 + g3) {
    attn_group<3>(n3 + (size_t)(t - g2) * 3, emb);
  } else if (t < g2 + g3 + g4) {
    attn_group<4>(n4 + (size_t)(t - g2 - g3) * 4, emb);
  }
}

// ---------------------------------------------------------------- pooled projection scatter
// out[ix] += sum_d emb[f,d] * w_expr[genes_oi[ix % n_genes], d]
__global__ void pool_kernel(const float* __restrict__ emb, const int* __restrict__ lci,
                            const int* __restrict__ genes_oi,
                            const float* __restrict__ wexpr, int F, int n_genes,
                            float* __restrict__ out) {
  int t = blockIdx.x * blockDim.x + threadIdx.x;
  if (t >= F) return;
  int ix = lci[t];
  int gcol = ix % n_genes;
  int g = genes_oi[gcol];
  const float* e = emb + (size_t)t * DD;
  const float* w = wexpr + (size_t)g * DD;
  float s = e[0] * w[0] + e[1] * w[1] + e[2] * w[2] + e[3] * w[3] + e[4] * w[4];
  atomicAdd(out + ix, s);
}

// ---------------------------------------------------------------- launch
extern "C" void kernel_launch(void* const* d_in, const int* in_sizes, int n_in,
                              void* d_out, int out_size, void* d_ws, size_t ws_size,
                              hipStream_t stream) {
  const float2* coords  = (const float2*)d_in[0];
  const int* gm         = (const int*)d_in[1];
  const int* n2         = (const int*)d_in[2];
  const int* n3         = (const int*)d_in[3];
  const int* n4         = (const int*)d_in[4];
  const int* lci        = (const int*)d_in[5];
  const int* genes_oi   = (const int*)d_in[6];
  const float* W        = (const float*)d_in[7];
  const float* wexpr    = (const float*)d_in[8];
  const float* bias     = (const float*)d_in[9];
  float* out            = (float*)d_out;

  const int F       = in_sizes[1];
  const int n_genes = in_sizes[6];
  const int g2 = in_sizes[2] / 2;
  const int g3 = in_sizes[3] / 3;
  const int g4 = in_sizes[4] / 4;

  char* ws = (char*)d_ws;
  size_t off = 0;
  float* emb   = (float*)(ws + off); off += (size_t)F * DD * sizeof(float);
  int* order   = (int*)(ws + off);   off += (size_t)F * sizeof(int);
  int* cnt     = (int*)(ws + off);   off += (size_t)n_genes * sizeof(int);
  int* starts  = (int*)(ws + off);   off += (size_t)(n_genes + 1) * sizeof(int);
  off = (off + 15) & ~(size_t)15;
  int* cursors = (int*)(ws + off);   off += (size_t)n_genes * sizeof(int);

  const int tb = 256;
  hipMemsetAsync(cnt, 0, (size_t)n_genes * sizeof(int), stream);
  hist_kernel<<<(F + tb - 1) / tb, tb, 0, stream>>>(gm, F, cnt);
  scan_kernel<<<1, 1024, 0, stream>>>(cnt, n_genes, starts, cursors);
  scatter_idx_kernel<<<(F + tb - 1) / tb, tb, 0, stream>>>(gm, F, cursors, order);
  embed_kernel<<<n_genes, 256, 0, stream>>>(coords, order, starts, W, emb);
  int gtot = g2 + g3 + g4;
  attn_kernel<<<(gtot + tb - 1) / tb, tb, 0, stream>>>(n2, g2, n3, g3, n4, g4, emb);
  int total4 = out_size / 4;
  init_out_kernel<<<(total4 + tb - 1) / tb, tb, 0, stream>>>(out, bias, genes_oi,
                                                             n_genes, total4);
  pool_kernel<<<(F + tb - 1) / tb, tb, 0, stream>>>(emb, lci, genes_oi, wexpr,
                                                    F, n_genes, out);
}

// Round 2
// 182.101 us; speedup vs baseline: 1.2066x; 1.2066x over previous
//
#include <hip/hip_runtime.h>
#include <math.h>

#define DD 5          // embedding dim
#define NFREQ 50      // frequencies per coordinate
#define NB 128        // sort blocks
// ENC_DIM = 4*NFREQ = 200; W row per gene = 200*5 = 1000 floats

// ---------------------------------------------------------------- init output
// out[c,g] = bias1[genes_oi[g]]; vectorized float4 (n_genes % 4 == 0)
__global__ void init_out_kernel(float* __restrict__ out,
                                const float* __restrict__ bias,
                                const int* __restrict__ genes_oi,
                                int n_genes, int total4) {
  int t = blockIdx.x * blockDim.x + threadIdx.x;
  if (t >= total4) return;
  int idx = t * 4;
  int j = idx % n_genes;          // n_genes multiple of 4 -> j..j+3 same row
  float4 v;
  v.x = bias[genes_oi[j + 0]];
  v.y = bias[genes_oi[j + 1]];
  v.z = bias[genes_oi[j + 2]];
  v.w = bias[genes_oi[j + 3]];
  reinterpret_cast<float4*>(out)[t] = v;
}

// ---------------------------------------------------------------- block-local histogram
// Each block histograms its contiguous chunk into LDS (depth ~1.5/bin), then
// writes per-block counts transposed: bc[bin*NB + b]. No global atomics.
__global__ __launch_bounds__(256) void blockhist_kernel(
    const int* __restrict__ gm, int F, int chunk,
    int* __restrict__ bc, int n_genes) {
  __shared__ int cnt[1000];
  for (int j = threadIdx.x; j < n_genes; j += blockDim.x) cnt[j] = 0;
  __syncthreads();
  int b = blockIdx.x;
  int lo = b * chunk;
  int hi = min(F, lo + chunk);
  for (int i = lo + threadIdx.x; i < hi; i += blockDim.x)
    atomicAdd(&cnt[gm[i]], 1);
  __syncthreads();
  for (int j = threadIdx.x; j < n_genes; j += blockDim.x)
    bc[j * NB + b] = cnt[j];
}

// ---------------------------------------------------------------- cross-block scan
// One block, 1024 threads. Thread j: in-place exclusive scan of bin j's NB
// block-counts (int4 contiguous), then LDS scan of bin totals -> starts[].
__global__ __launch_bounds__(1024) void binscan_kernel(
    int* __restrict__ bc, int n_genes, int* __restrict__ starts) {
  __shared__ int tot[1024];
  int j = threadIdx.x;
  int run = 0;
  if (j < n_genes) {
    int4* p = (int4*)(bc + (size_t)j * NB);
#pragma unroll 4
    for (int k = 0; k < NB / 4; ++k) {
      int4 v = p[k];
      int4 e;
      e.x = run; run += v.x;
      e.y = run; run += v.y;
      e.z = run; run += v.z;
      e.w = run; run += v.w;
      p[k] = e;
    }
  }
  tot[j] = (j < n_genes) ? run : 0;   // run == bin total
  __syncthreads();
  for (int off = 1; off < 1024; off <<= 1) {
    int v2 = (j >= off) ? tot[j - off] : 0;
    __syncthreads();
    tot[j] += v2;
    __syncthreads();
  }
  if (j < n_genes) starts[j] = tot[j] - run;   // exclusive
  if (j == n_genes - 1) starts[n_genes] = tot[j];
}

// ---------------------------------------------------------------- scatter by gene
// LDS cursors seeded with this block's global offset per bin; LDS atomics only.
__global__ __launch_bounds__(256) void blockscatter_kernel(
    const int* __restrict__ gm, int F, int chunk,
    const int* __restrict__ bc, const int* __restrict__ starts,
    int* __restrict__ order, int n_genes) {
  __shared__ int cur[1000];
  int b = blockIdx.x;
  for (int j = threadIdx.x; j < n_genes; j += blockDim.x)
    cur[j] = starts[j] + bc[j * NB + b];
  __syncthreads();
  int lo = b * chunk;
  int hi = min(F, lo + chunk);
  for (int i = lo + threadIdx.x; i < hi; i += blockDim.x) {
    int g = gm[i];
    int p = atomicAdd(&cur[g], 1);
    order[p] = i;
  }
}

// ---------------------------------------------------------------- fragment embedding
// One block per gene: W addresses are wave-uniform -> scalar (SMEM) loads.
__global__ __launch_bounds__(256) void embed_kernel(
    const float2* __restrict__ coords, const int* __restrict__ order,
    const int* __restrict__ starts, const float* __restrict__ W,
    float* __restrict__ emb) {
  int g = blockIdx.x;
  int s0 = starts[g];
  int s1 = starts[g + 1];
  const float* __restrict__ Wg = W + (size_t)g * (4 * NFREQ * DD);

  for (int i = s0 + threadIdx.x; i < s1; i += blockDim.x) {
    int f = order[i];
    float2 xy = coords[f];
    float a0d0 = 0.f, a0d1 = 0.f, a0d2 = 0.f, a0d3 = 0.f, a0d4 = 0.f;
    for (int k = 0; k < NFREQ; ++k) {
      // freq_{k+1} = 1000^(-2(k+1)/50) = 2^(-0.398631371*(k+1))
      float fr = exp2f(-0.39863137f * (float)(k + 1));
      float ax = xy.x * fr;
      float ay = xy.y * fr;
      float sx = __sinf(ax), cx = __cosf(ax);
      float sy = __sinf(ay), cy = __cosf(ay);
      const float* w0s = Wg + (2 * k) * DD;               // coord0 sin row
      const float* w0c = w0s + DD;                        // coord0 cos row
      const float* w1s = Wg + (2 * NFREQ + 2 * k) * DD;   // coord1 sin row
      const float* w1c = w1s + DD;                        // coord1 cos row
      a0d0 += sx * w0s[0] + cx * w0c[0] + sy * w1s[0] + cy * w1c[0];
      a0d1 += sx * w0s[1] + cx * w0c[1] + sy * w1s[1] + cy * w1c[1];
      a0d2 += sx * w0s[2] + cx * w0c[2] + sy * w1s[2] + cy * w1c[2];
      a0d3 += sx * w0s[3] + cx * w0c[3] + sy * w1s[3] + cy * w1c[3];
      a0d4 += sx * w0s[4] + cx * w0c[4] + sy * w1s[4] + cy * w1c[4];
    }
    float* e = emb + (size_t)f * DD;
    e[0] = 1.f / (1.f + __expf(-a0d0));
    e[1] = 1.f / (1.f + __expf(-a0d1));
    e[2] = 1.f / (1.f + __expf(-a0d2));
    e[3] = 1.f / (1.f + __expf(-a0d3));
    e[4] = 1.f / (1.f + __expf(-a0d4));
  }
}

// ---------------------------------------------------------------- ragged self-attention
template <int SZ>
__device__ __forceinline__ void attn_group(const int* __restrict__ idx,
                                           float* __restrict__ emb) {
  int fid[SZ];
  float x[SZ][DD];
#pragma unroll
  for (int a = 0; a < SZ; ++a) {
    fid[a] = idx[a];
    const float* p = emb + (size_t)fid[a] * DD;
#pragma unroll
    for (int d = 0; d < DD; ++d) x[a][d] = p[d];
  }
  const float scale = rsqrtf((float)SZ);   // reference scales by sqrt(seq_len)
  float o[SZ][DD];
#pragma unroll
  for (int a = 0; a < SZ; ++a) {
    float sc[SZ];
    float m = -1e30f;
#pragma unroll
    for (int b = 0; b < SZ; ++b) {
      float dt = 0.f;
#pragma unroll
      for (int d = 0; d < DD; ++d) dt += x[a][d] * x[b][d];
      sc[b] = dt * scale;
      m = fmaxf(m, sc[b]);
    }
    float sum = 0.f;
#pragma unroll
    for (int b = 0; b < SZ; ++b) {
      sc[b] = __expf(sc[b] - m);
      sum += sc[b];
    }
    float inv = 1.f / sum;
#pragma unroll
    for (int d = 0; d < DD; ++d) {
      float acc = 0.f;
#pragma unroll
      for (int b = 0; b < SZ; ++b) acc += sc[b] * x[b][d];
      o[a][d] = acc * inv;
    }
  }
#pragma unroll
  for (int a = 0; a < SZ; ++a) {
    float* p = emb + (size_t)fid[a] * DD;
#pragma unroll
    for (int d = 0; d < DD; ++d) p[d] = o[a][d];
  }
}

__global__ void attn_kernel(const int* __restrict__ n2, int g2,
                            const int* __restrict__ n3, int g3,
                            const int* __restrict__ n4, int g4,
                            float* __restrict__ emb) {
  int t = blockIdx.x * blockDim.x + threadIdx.x;
  if (t < g2) {
    attn_group<2>(n2 + (size_t)t * 2, emb);
  } else if (t < g2 + g3) {
    attn_group<3>(n3 + (size_t)(t - g2) * 3, emb);
  } else if (t < g2 + g3 + g4) {
    attn_group<4>(n4 + (size_t)(t - g2 - g3) * 4, emb);
  }
}

// ---------------------------------------------------------------- pooled projection scatter
// out[ix] += sum_d emb[f,d] * w_expr[genes_oi[ix % n_genes], d]
__global__ void pool_kernel(const float* __restrict__ emb, const int* __restrict__ lci,
                            const int* __restrict__ genes_oi,
                            const float* __restrict__ wexpr, int F, int n_genes,
                            float* __restrict__ out) {
  int t = blockIdx.x * blockDim.x + threadIdx.x;
  if (t >= F) return;
  int ix = lci[t];
  int gcol = ix % n_genes;
  int g = genes_oi[gcol];
  const float* e = emb + (size_t)t * DD;
  const float* w = wexpr + (size_t)g * DD;
  float s = e[0] * w[0] + e[1] * w[1] + e[2] * w[2] + e[3] * w[3] + e[4] * w[4];
  atomicAdd(out + ix, s);
}

// ---------------------------------------------------------------- launch
extern "C" void kernel_launch(void* const* d_in, const int* in_sizes, int n_in,
                              void* d_out, int out_size, void* d_ws, size_t ws_size,
                              hipStream_t stream) {
  const float2* coords  = (const float2*)d_in[0];
  const int* gm         = (const int*)d_in[1];
  const int* n2         = (const int*)d_in[2];
  const int* n3         = (const int*)d_in[3];
  const int* n4         = (const int*)d_in[4];
  const int* lci        = (const int*)d_in[5];
  const int* genes_oi   = (const int*)d_in[6];
  const float* W        = (const float*)d_in[7];
  const float* wexpr    = (const float*)d_in[8];
  const float* bias     = (const float*)d_in[9];
  float* out            = (float*)d_out;

  const int F       = in_sizes[1];
  const int n_genes = in_sizes[6];
  const int g2 = in_sizes[2] / 2;
  const int g3 = in_sizes[3] / 3;
  const int g4 = in_sizes[4] / 4;

  char* ws = (char*)d_ws;
  size_t off = 0;
  float* emb   = (float*)(ws + off); off += (size_t)F * DD * sizeof(float);
  int* order   = (int*)(ws + off);   off += (size_t)F * sizeof(int);
  int* bc      = (int*)(ws + off);   off += (size_t)n_genes * NB * sizeof(int);
  int* starts  = (int*)(ws + off);   off += (size_t)(n_genes + 1) * sizeof(int);

  const int tb = 256;
  const int chunk = (F + NB - 1) / NB;

  blockhist_kernel<<<NB, tb, 0, stream>>>(gm, F, chunk, bc, n_genes);
  binscan_kernel<<<1, 1024, 0, stream>>>(bc, n_genes, starts);
  blockscatter_kernel<<<NB, tb, 0, stream>>>(gm, F, chunk, bc, starts, order, n_genes);
  embed_kernel<<<n_genes, 256, 0, stream>>>(coords, order, starts, W, emb);
  int gtot = g2 + g3 + g4;
  attn_kernel<<<(gtot + tb - 1) / tb, tb, 0, stream>>>(n2, g2, n3, g3, n4, g4, emb);
  int total4 = out_size / 4;
  init_out_kernel<<<(total4 + tb - 1) / tb, tb, 0, stream>>>(out, bias, genes_oi,
                                                             n_genes, total4);
  pool_kernel<<<(F + tb - 1) / tb, tb, 0, stream>>>(emb, lci, genes_oi, wexpr,
                                                    F, n_genes, out);
}

// Round 3
// 146.656 us; speedup vs baseline: 1.4982x; 1.2417x over previous
//
#include <hip/hip_runtime.h>
#include <math.h>

#define DD 5          // embedding dim
#define NFREQ 50      // frequencies per coordinate
#define NB 128        // sort blocks
// ENC_DIM = 4*NFREQ = 200; W row per gene = 200*5 = 1000 floats

// ---------------------------------------------------------------- init output
// out[c,g] = bias1[genes_oi[g]]; vectorized float4 (n_genes % 4 == 0)
__global__ void init_out_kernel(float* __restrict__ out,
                                const float* __restrict__ bias,
                                const int* __restrict__ genes_oi,
                                int n_genes, int total4) {
  int t = blockIdx.x * blockDim.x + threadIdx.x;
  if (t >= total4) return;
  int idx = t * 4;
  int j = idx % n_genes;          // n_genes multiple of 4 -> j..j+3 same row
  float4 v;
  v.x = bias[genes_oi[j + 0]];
  v.y = bias[genes_oi[j + 1]];
  v.z = bias[genes_oi[j + 2]];
  v.w = bias[genes_oi[j + 3]];
  reinterpret_cast<float4*>(out)[t] = v;
}

// ---------------------------------------------------------------- block-local histogram
// Each block histograms its contiguous chunk into LDS (depth ~1.5/bin), then
// writes per-block counts transposed: bc[bin*NB + b]. No global atomics.
__global__ __launch_bounds__(256) void blockhist_kernel(
    const int* __restrict__ gm, int F, int chunk,
    int* __restrict__ bc, int n_genes) {
  __shared__ int cnt[1000];
  for (int j = threadIdx.x; j < n_genes; j += blockDim.x) cnt[j] = 0;
  __syncthreads();
  int b = blockIdx.x;
  int lo = b * chunk;
  int hi = min(F, lo + chunk);
  for (int i = lo + threadIdx.x; i < hi; i += blockDim.x)
    atomicAdd(&cnt[gm[i]], 1);
  __syncthreads();
  for (int j = threadIdx.x; j < n_genes; j += blockDim.x)
    bc[j * NB + b] = cnt[j];
}

// ---------------------------------------------------------------- per-bin wave scan
// One wave per bin: exclusive-scan the bin's NB=128 block counts in-register
// (shfl_up), write back, emit bin total. 250 blocks -> fleet-parallel.
__global__ __launch_bounds__(256) void binwavescan_kernel(
    int* __restrict__ bc, int n_genes, int* __restrict__ totals) {
  int lane = threadIdx.x & 63;
  int wv = (blockIdx.x * blockDim.x + threadIdx.x) >> 6;
  if (wv >= n_genes) return;
  int* row = bc + (size_t)wv * NB;
  int v0 = row[lane];
  int v1 = row[64 + lane];
  int s0 = v0;
#pragma unroll
  for (int off = 1; off < 64; off <<= 1) {
    int t = __shfl_up(s0, off);
    if (lane >= off) s0 += t;
  }
  int tot0 = __shfl(s0, 63);
  int s1 = v1;
#pragma unroll
  for (int off = 1; off < 64; off <<= 1) {
    int t = __shfl_up(s1, off);
    if (lane >= off) s1 += t;
  }
  s1 += tot0;
  row[lane] = s0 - v0;        // exclusive prefix, first half
  row[64 + lane] = s1 - v1;   // exclusive prefix, second half
  if (lane == 63) totals[wv] = s1;
}

// ---------------------------------------------------------------- scan bin totals
// Single block over 1000 totals (4 KB) -> starts[]. LDS Hillis-Steele.
__global__ __launch_bounds__(1024) void starts_scan_kernel(
    const int* __restrict__ totals, int n_genes, int* __restrict__ starts) {
  __shared__ int s[1024];
  int j = threadIdx.x;
  int v = (j < n_genes) ? totals[j] : 0;
  s[j] = v;
  __syncthreads();
  for (int off = 1; off < 1024; off <<= 1) {
    int t2 = (j >= off) ? s[j - off] : 0;
    __syncthreads();
    s[j] += t2;
    __syncthreads();
  }
  if (j < n_genes) starts[j] = s[j] - v;   // exclusive
  if (j == n_genes - 1) starts[n_genes] = s[j];
}

// ---------------------------------------------------------------- scatter by gene
// LDS cursors seeded with this block's global offset per bin; LDS atomics only.
__global__ __launch_bounds__(256) void blockscatter_kernel(
    const int* __restrict__ gm, int F, int chunk,
    const int* __restrict__ bc, const int* __restrict__ starts,
    int* __restrict__ order, int n_genes) {
  __shared__ int cur[1000];
  int b = blockIdx.x;
  for (int j = threadIdx.x; j < n_genes; j += blockDim.x)
    cur[j] = starts[j] + bc[j * NB + b];
  __syncthreads();
  int lo = b * chunk;
  int hi = min(F, lo + chunk);
  for (int i = lo + threadIdx.x; i < hi; i += blockDim.x) {
    int g = gm[i];
    int p = atomicAdd(&cur[g], 1);
    order[p] = i;
  }
}

// ---------------------------------------------------------------- fragment embedding
// One block per gene: W addresses are wave-uniform -> scalar (SMEM) loads.
__global__ __launch_bounds__(256) void embed_kernel(
    const float2* __restrict__ coords, const int* __restrict__ order,
    const int* __restrict__ starts, const float* __restrict__ W,
    float* __restrict__ emb) {
  int g = blockIdx.x;
  int s0 = starts[g];
  int s1 = starts[g + 1];
  const float* __restrict__ Wg = W + (size_t)g * (4 * NFREQ * DD);

  for (int i = s0 + threadIdx.x; i < s1; i += blockDim.x) {
    int f = order[i];
    float2 xy = coords[f];
    float a0d0 = 0.f, a0d1 = 0.f, a0d2 = 0.f, a0d3 = 0.f, a0d4 = 0.f;
    for (int k = 0; k < NFREQ; ++k) {
      // freq_{k+1} = 1000^(-2(k+1)/50) = 2^(-0.398631371*(k+1))
      float fr = exp2f(-0.39863137f * (float)(k + 1));
      float ax = xy.x * fr;
      float ay = xy.y * fr;
      float sx = __sinf(ax), cx = __cosf(ax);
      float sy = __sinf(ay), cy = __cosf(ay);
      const float* w0s = Wg + (2 * k) * DD;               // coord0 sin row
      const float* w0c = w0s + DD;                        // coord0 cos row
      const float* w1s = Wg + (2 * NFREQ + 2 * k) * DD;   // coord1 sin row
      const float* w1c = w1s + DD;                        // coord1 cos row
      a0d0 += sx * w0s[0] + cx * w0c[0] + sy * w1s[0] + cy * w1c[0];
      a0d1 += sx * w0s[1] + cx * w0c[1] + sy * w1s[1] + cy * w1c[1];
      a0d2 += sx * w0s[2] + cx * w0c[2] + sy * w1s[2] + cy * w1c[2];
      a0d3 += sx * w0s[3] + cx * w0c[3] + sy * w1s[3] + cy * w1c[3];
      a0d4 += sx * w0s[4] + cx * w0c[4] + sy * w1s[4] + cy * w1c[4];
    }
    float* e = emb + (size_t)f * DD;
    e[0] = 1.f / (1.f + __expf(-a0d0));
    e[1] = 1.f / (1.f + __expf(-a0d1));
    e[2] = 1.f / (1.f + __expf(-a0d2));
    e[3] = 1.f / (1.f + __expf(-a0d3));
    e[4] = 1.f / (1.f + __expf(-a0d4));
  }
}

// ---------------------------------------------------------------- ragged self-attention
template <int SZ>
__device__ __forceinline__ void attn_group(const int* __restrict__ idx,
                                           float* __restrict__ emb) {
  int fid[SZ];
  float x[SZ][DD];
#pragma unroll
  for (int a = 0; a < SZ; ++a) {
    fid[a] = idx[a];
    const float* p = emb + (size_t)fid[a] * DD;
#pragma unroll
    for (int d = 0; d < DD; ++d) x[a][d] = p[d];
  }
  const float scale = rsqrtf((float)SZ);   // reference scales by sqrt(seq_len)
  float o[SZ][DD];
#pragma unroll
  for (int a = 0; a < SZ; ++a) {
    float sc[SZ];
    float m = -1e30f;
#pragma unroll
    for (int b = 0; b < SZ; ++b) {
      float dt = 0.f;
#pragma unroll
      for (int d = 0; d < DD; ++d) dt += x[a][d] * x[b][d];
      sc[b] = dt * scale;
      m = fmaxf(m, sc[b]);
    }
    float sum = 0.f;
#pragma unroll
    for (int b = 0; b < SZ; ++b) {
      sc[b] = __expf(sc[b] - m);
      sum += sc[b];
    }
    float inv = 1.f / sum;
#pragma unroll
    for (int d = 0; d < DD; ++d) {
      float acc = 0.f;
#pragma unroll
      for (int b = 0; b < SZ; ++b) acc += sc[b] * x[b][d];
      o[a][d] = acc * inv;
    }
  }
#pragma unroll
  for (int a = 0; a < SZ; ++a) {
    float* p = emb + (size_t)fid[a] * DD;
#pragma unroll
    for (int d = 0; d < DD; ++d) p[d] = o[a][d];
  }
}

__global__ void attn_kernel(const int* __restrict__ n2, int g2,
                            const int* __restrict__ n3, int g3,
                            const int* __restrict__ n4, int g4,
                            float* __restrict__ emb) {
  int t = blockIdx.x * blockDim.x + threadIdx.x;
  if (t < g2) {
    attn_group<2>(n2 + (size_t)t * 2, emb);
  } else if (t < g2 + g3) {
    attn_group<3>(n3 + (size_t)(t - g2) * 3, emb);
  } else if (t < g2 + g3 + g4) {
    attn_group<4>(n4 + (size_t)(t - g2 - g3) * 4, emb);
  }
}

// ---------------------------------------------------------------- pooled projection scatter
// out[ix] += sum_d emb[f,d] * w_expr[genes_oi[ix % n_genes], d]
__global__ void pool_kernel(const float* __restrict__ emb, const int* __restrict__ lci,
                            const int* __restrict__ genes_oi,
                            const float* __restrict__ wexpr, int F, int n_genes,
                            float* __restrict__ out) {
  int t = blockIdx.x * blockDim.x + threadIdx.x;
  if (t >= F) return;
  int ix = lci[t];
  int gcol = ix % n_genes;
  int g = genes_oi[gcol];
  const float* e = emb + (size_t)t * DD;
  const float* w = wexpr + (size_t)g * DD;
  float s = e[0] * w[0] + e[1] * w[1] + e[2] * w[2] + e[3] * w[3] + e[4] * w[4];
  atomicAdd(out + ix, s);
}

// ---------------------------------------------------------------- launch
extern "C" void kernel_launch(void* const* d_in, const int* in_sizes, int n_in,
                              void* d_out, int out_size, void* d_ws, size_t ws_size,
                              hipStream_t stream) {
  const float2* coords  = (const float2*)d_in[0];
  const int* gm         = (const int*)d_in[1];
  const int* n2         = (const int*)d_in[2];
  const int* n3         = (const int*)d_in[3];
  const int* n4         = (const int*)d_in[4];
  const int* lci        = (const int*)d_in[5];
  const int* genes_oi   = (const int*)d_in[6];
  const float* W        = (const float*)d_in[7];
  const float* wexpr    = (const float*)d_in[8];
  const float* bias     = (const float*)d_in[9];
  float* out            = (float*)d_out;

  const int F       = in_sizes[1];
  const int n_genes = in_sizes[6];
  const int g2 = in_sizes[2] / 2;
  const int g3 = in_sizes[3] / 3;
  const int g4 = in_sizes[4] / 4;

  char* ws = (char*)d_ws;
  size_t off = 0;
  float* emb   = (float*)(ws + off); off += (size_t)F * DD * sizeof(float);
  int* order   = (int*)(ws + off);   off += (size_t)F * sizeof(int);
  int* bc      = (int*)(ws + off);   off += (size_t)n_genes * NB * sizeof(int);
  int* starts  = (int*)(ws + off);   off += (size_t)(n_genes + 1) * sizeof(int);
  int* totals  = (int*)(ws + off);   off += (size_t)n_genes * sizeof(int);

  const int tb = 256;
  const int chunk = (F + NB - 1) / NB;

  blockhist_kernel<<<NB, tb, 0, stream>>>(gm, F, chunk, bc, n_genes);
  int scan_blocks = (n_genes * 64 + tb - 1) / tb;   // one wave per bin
  binwavescan_kernel<<<scan_blocks, tb, 0, stream>>>(bc, n_genes, totals);
  starts_scan_kernel<<<1, 1024, 0, stream>>>(totals, n_genes, starts);
  blockscatter_kernel<<<NB, tb, 0, stream>>>(gm, F, chunk, bc, starts, order, n_genes);
  embed_kernel<<<n_genes, 256, 0, stream>>>(coords, order, starts, W, emb);
  int gtot = g2 + g3 + g4;
  attn_kernel<<<(gtot + tb - 1) / tb, tb, 0, stream>>>(n2, g2, n3, g3, n4, g4, emb);
  int total4 = out_size / 4;
  init_out_kernel<<<(total4 + tb - 1) / tb, tb, 0, stream>>>(out, bias, genes_oi,
                                                             n_genes, total4);
  pool_kernel<<<(F + tb - 1) / tb, tb, 0, stream>>>(emb, lci, genes_oi, wexpr,
                                                    F, n_genes, out);
}